// Round 3
// baseline (210.389 us; speedup 1.0000x reference)
//
#include <hip/hip_runtime.h>
#include <hip/hip_bf16.h>
#include <math.h>

// MoE top-2: B=4,S=2048,H=1024,E=8,K=2. fp32 in/out, f16 MFMA compute.
#define TOK 8192
#define HD 1024
#define NE 8
#define SLOTS 18432     // 16384 + per-expert 256-pad (BM=256 tiles)
#define NGRP 512        // 16-token scatter groups
#define GRPSZ 16

typedef _Float16 half8 __attribute__((ext_vector_type(8)));
typedef _Float16 half4v __attribute__((ext_vector_type(4)));
typedef float floatx4 __attribute__((ext_vector_type(4)));

#define WAIT_VMCNT0() asm volatile("s_waitcnt vmcnt(0)" ::: "memory")
#define WAIT_LGKM0()  asm volatile("s_waitcnt lgkmcnt(0)" ::: "memory")

// ---- Fused score + weight-convert (block-role split) ----
__global__ __launch_bounds__(256) void score_cvt(
    const float* __restrict__ x,
    const float* __restrict__ rw,
    const float* __restrict__ rb,
    const float* __restrict__ ew,
    _Float16* __restrict__ xh,
    _Float16* __restrict__ wh,
    int* __restrict__ epair,
    float* __restrict__ w1out,
    int* __restrict__ hist) {          // [NE][NGRP]
  const int tid = threadIdx.x;
  const int blk = blockIdx.x;
  if (blk >= NGRP) {
    const int g = (blk - NGRP) * 256 + tid;
    const float4* src = (const float4*)ew;
    half4v* dst = (half4v*)wh;
#pragma unroll
    for (int j = 0; j < 4; ++j) {
      float4 v = src[g + 524288 * j];
      half4v h = {(_Float16)v.x, (_Float16)v.y, (_Float16)v.z, (_Float16)v.w};
      dst[g + 524288 * j] = h;
    }
    return;
  }
  const int lane = tid & 63;
  const int wid = tid >> 6;
  __shared__ int hcnt[NE];
  if (tid < NE) hcnt[tid] = 0;
  __syncthreads();

#pragma unroll
  for (int i = 0; i < 4; ++i) {
    const int t = blk * GRPSZ + wid * 4 + i;
    const float4* xp = (const float4*)(x + (size_t)t * HD);
    float4 xr[4];
#pragma unroll
    for (int k = 0; k < 4; ++k) xr[k] = xp[lane + 64 * k];
    _Float16* xo = xh + (size_t)t * HD;
#pragma unroll
    for (int k = 0; k < 4; ++k) {
      half4v h = {(_Float16)xr[k].x, (_Float16)xr[k].y,
                  (_Float16)xr[k].z, (_Float16)xr[k].w};
      *(half4v*)(xo + (lane + 64 * k) * 4) = h;
    }
    float sc[NE];
#pragma unroll
    for (int e = 0; e < NE; ++e) {
      const float4* wp = (const float4*)(rw + e * HD);
      float a = 0.f;
#pragma unroll
      for (int k = 0; k < 4; ++k) {
        float4 w = wp[lane + 64 * k];
        a += xr[k].x * w.x + xr[k].y * w.y + xr[k].z * w.z + xr[k].w * w.w;
      }
#pragma unroll
      for (int off = 32; off > 0; off >>= 1) a += __shfl_xor(a, off);
      sc[e] = a + rb[e];
    }
    // top-2, strict > (ties -> lowest index, matches jax.lax.top_k)
    float b1 = sc[0]; int e1 = 0;
#pragma unroll
    for (int e = 1; e < NE; ++e) if (sc[e] > b1) { b1 = sc[e]; e1 = e; }
    float b2 = -1e30f; int e2 = 0;
#pragma unroll
    for (int e = 0; e < NE; ++e) { if (e != e1 && sc[e] > b2) { b2 = sc[e]; e2 = e; } }
    if (lane == 0) {
      epair[t] = e1 | (e2 << 8);
      w1out[t] = 1.f / (1.f + expf(b2 - b1));  // renormalized top-2 softmax
      atomicAdd(&hcnt[e1], 1);
      atomicAdd(&hcnt[e2], 1);
    }
  }
  __syncthreads();
  if (tid < NE) hist[tid * NGRP + blk] = hcnt[tid];
}

// ---- Scatter: each block recomputes its prefix from hist (no global sync) --
__global__ __launch_bounds__(256) void moe_scatter(
    const int* __restrict__ hist,
    const int* __restrict__ epair,
    const float* __restrict__ w1in,
    int* __restrict__ cntp,
    int* __restrict__ basep,
    int* __restrict__ tok_list,
    float* __restrict__ tok_w,
    int* __restrict__ slot_of) {
  const int tid = threadIdx.x;
  const int blk = blockIdx.x;
  __shared__ int pre_s[NE], tot_s[NE], alloc_s[NE];
  {
    const int e = tid >> 5;
    const int sl = tid & 31;
    int p = 0, tt = 0;
#pragma unroll
    for (int j = 0; j < 16; ++j) {
      int g = sl + 32 * j;
      int h = hist[e * NGRP + g];
      tt += h;
      p += (g < blk) ? h : 0;
    }
#pragma unroll
    for (int off = 16; off > 0; off >>= 1) {
      p += __shfl_xor(p, off);
      tt += __shfl_xor(tt, off);
    }
    if (sl == 0) { pre_s[e] = p; tot_s[e] = tt; }
  }
  __syncthreads();
  if (tid == 0) {
    int b = 0;
    for (int e = 0; e < NE; ++e) {
      alloc_s[e] = b + pre_s[e];
      if (blk == 0) { cntp[e * 64] = tot_s[e]; basep[e] = b; }
      b += (tot_s[e] + 255) & ~255;   // 256-pad: BM=256 tiles never straddle
    }
  }
  __syncthreads();
  if (tid < GRPSZ) {
    const int t = blk * GRPSZ + tid;
    int ep = epair[t];
    int e1 = ep & 0xff, e2 = ep >> 8;
    float w1 = w1in[t];
    int s1 = atomicAdd(&alloc_s[e1], 1);
    tok_list[s1] = t; tok_w[s1] = w1; slot_of[2 * t] = s1;
    int s2 = atomicAdd(&alloc_s[e2], 1);
    tok_list[s2] = t; tok_w[s2] = 1.f - w1; slot_of[2 * t + 1] = s2;
  }
}

// ---- Grouped expert GEMM: 256x256 tile, BK=64, 8-wave 4-phase schedule ----
// R2 lesson: 128^2 2-phase is structurally stall-bound at ~550 TF (m233):
// 32 MFMA/wave per K-step (~400 cyc) can't cover ~900 cyc load latency,
// counted vmcnt or not. Port of the verified 256^2 8-phase template (m201):
// 8 waves (2Mx4N), per-wave 128x64 out, 64 MFMA/K-tile in 4 quadrant phases
// of 16 MFMA each. All 8 staging units of tile t+1 issue by phase 2 ->
// boundary vmcnt(0) waits on loads issued ~3 phases (~1000 cyc) earlier.
// setprio(1) around MFMA clusters (T5: +21-25%, gated on phase structure).
// 3-bit XOR chunk swizzle (verified 0 bank conflicts): global chunk g of
// row r at LDS pos g^(r&7); reads use pos cc^(l15&7) -> <=2-way (free).
// Expert<->XCD pinning: blockIdx.x = expert = XCD (round-robin dispatch) ->
// each XCD's 32 CUs share one expert's 2 MB weight panel in its L2.
// EPI=1: f16 store to compacted scratch; EPI=0: fp32 atomicAdd to out.
template <int EPI>
__global__ __launch_bounds__(512, 2) void moe_gemm(
    const _Float16* __restrict__ Ah, const _Float16* __restrict__ Bh,
    const float* __restrict__ eb,
    const int* __restrict__ cntp, const int* __restrict__ base,
    const int* __restrict__ tok_list, const float* __restrict__ tok_w,
    _Float16* __restrict__ scratch, float* __restrict__ out) {
  const int e = blockIdx.x;                 // expert == XCD id
  const int ce = cntp[e * 64];
  const int m0 = (blockIdx.y >> 2) << 8;    // m-tile * 256
  if (m0 >= ce) return;
  const int nb = (blockIdx.y & 3) << 8;     // n-tile * 256
  const int sbase = base[e];
  const int tid = threadIdx.x;
  const int lane = tid & 63;
  const int wid = tid >> 6;                 // 0..7
  const int wm = wid >> 2, wn = wid & 3;    // wave tile: rows wm*128, cols wn*64

  __shared__ _Float16 A_s[2][256 * 64];
  __shared__ _Float16 B_s[2][256 * 64];
  __shared__ int tok_s[256];
  __shared__ float w_s[256];

  if (tid < 256) {
    int tk = 0; float w = 0.f;
    if (m0 + tid < ce) { tk = tok_list[sbase + m0 + tid]; w = tok_w[sbase + m0 + tid]; }
    tok_s[tid] = tk; w_s[tid] = w;
  }
  __syncthreads();

  floatx4 acc[8][4];
  floatx4 zero = {0.f, 0.f, 0.f, 0.f};
#pragma unroll
  for (int i = 0; i < 8; ++i)
#pragma unroll
    for (int j = 0; j < 4; ++j) acc[i][j] = zero;

  const int wbase = e * HD * HD;            // fits int: <= 7*2^20
  // staging: 8 units/K-tile (4 A + 4 B), each unit = 64 rows = one
  // global_load_lds per wave (8 rows x 8 chunks, 16B/lane).
  const int rloc = lane >> 3, sub = lane & 7;
  const int g8 = (sub ^ rloc) * 8;          // row&7 == rloc for our rows
  int agoff[4], bgoff[4];
#pragma unroll
  for (int u = 0; u < 4; ++u) {
    const int row = u * 64 + wid * 8 + rloc;
    agoff[u] = tok_s[row] * HD + g8;
    bgoff[u] = wbase + (nb + row) * HD + g8;
  }
  const int l15 = lane & 15, q4 = lane >> 4;
  // fragment LDS chunk offsets (XOR swizzle), rows stride 64 f16
  const int ck0 = ((q4)     ^ (l15 & 7)) * 8;
  const int ck1 = ((4 + q4) ^ (l15 & 7)) * 8;
  const int arow0 = (wm * 128 + l15) * 64;  // + i*16*64
  const int brow0 = (wn * 64  + l15) * 64;  // + j*16*64

  auto stageA = [&](int buf, int k0) {
#pragma unroll
    for (int u = 0; u < 4; ++u) {
      const int r0 = u * 64 + wid * 8;
      __builtin_amdgcn_global_load_lds(
          (const __attribute__((address_space(1))) unsigned int*)(Ah + agoff[u] + k0),
          (__attribute__((address_space(3))) unsigned int*)&A_s[buf][r0 * 64], 16, 0, 0);
    }
  };
  auto stageB = [&](int buf, int k0) {
#pragma unroll
    for (int u = 0; u < 4; ++u) {
      const int r0 = u * 64 + wid * 8;
      __builtin_amdgcn_global_load_lds(
          (const __attribute__((address_space(1))) unsigned int*)(Bh + bgoff[u] + k0),
          (__attribute__((address_space(3))) unsigned int*)&B_s[buf][r0 * 64], 16, 0, 0);
    }
  };

  stageA(0, 0);
  stageB(0, 0);
  WAIT_VMCNT0();
  __builtin_amdgcn_s_barrier();

#pragma unroll 2
  for (int t = 0; t < 16; ++t) {
    const int cur = t & 1, nxt = cur ^ 1;
    const int kn = (t + 1) * 64;
    half8 afr[4][2], b01[2][2], b23[2][2];

    // ---- phase 1: read A(i0..3) + B(j0..1); stage next A; MFMA Q(0,0) ----
#pragma unroll
    for (int i = 0; i < 4; ++i) {
      afr[i][0] = *(const half8*)&A_s[cur][arow0 + i * 16 * 64 + ck0];
      afr[i][1] = *(const half8*)&A_s[cur][arow0 + i * 16 * 64 + ck1];
    }
#pragma unroll
    for (int j = 0; j < 2; ++j) {
      b01[j][0] = *(const half8*)&B_s[cur][brow0 + j * 16 * 64 + ck0];
      b01[j][1] = *(const half8*)&B_s[cur][brow0 + j * 16 * 64 + ck1];
    }
    if (t < 15) stageA(nxt, kn);
    __builtin_amdgcn_s_barrier();
    WAIT_LGKM0();
    __builtin_amdgcn_sched_barrier(0);
    __builtin_amdgcn_s_setprio(1);
#pragma unroll
    for (int i = 0; i < 4; ++i)
#pragma unroll
      for (int j = 0; j < 2; ++j) {
        acc[i][j] = __builtin_amdgcn_mfma_f32_16x16x32_f16(afr[i][0], b01[j][0], acc[i][j], 0, 0, 0);
        acc[i][j] = __builtin_amdgcn_mfma_f32_16x16x32_f16(afr[i][1], b01[j][1], acc[i][j], 0, 0, 0);
      }
    __builtin_amdgcn_s_setprio(0);
    __builtin_amdgcn_s_barrier();

    // ---- phase 2: read B(j2..3); stage next B; MFMA Q(0,1) ----
#pragma unroll
    for (int j = 0; j < 2; ++j) {
      b23[j][0] = *(const half8*)&B_s[cur][brow0 + (j + 2) * 16 * 64 + ck0];
      b23[j][1] = *(const half8*)&B_s[cur][brow0 + (j + 2) * 16 * 64 + ck1];
    }
    if (t < 15) stageB(nxt, kn);
    __builtin_amdgcn_s_barrier();
    WAIT_LGKM0();
    __builtin_amdgcn_sched_barrier(0);
    __builtin_amdgcn_s_setprio(1);
#pragma unroll
    for (int i = 0; i < 4; ++i)
#pragma unroll
      for (int j = 0; j < 2; ++j) {
        acc[i][j + 2] = __builtin_amdgcn_mfma_f32_16x16x32_f16(afr[i][0], b23[j][0], acc[i][j + 2], 0, 0, 0);
        acc[i][j + 2] = __builtin_amdgcn_mfma_f32_16x16x32_f16(afr[i][1], b23[j][1], acc[i][j + 2], 0, 0, 0);
      }
    __builtin_amdgcn_s_setprio(0);
    __builtin_amdgcn_s_barrier();

    // ---- phase 3: read A(i4..7); MFMA Q(1,1) ----
#pragma unroll
    for (int i = 0; i < 4; ++i) {
      afr[i][0] = *(const half8*)&A_s[cur][arow0 + (i + 4) * 16 * 64 + ck0];
      afr[i][1] = *(const half8*)&A_s[cur][arow0 + (i + 4) * 16 * 64 + ck1];
    }
    __builtin_amdgcn_s_barrier();
    WAIT_LGKM0();
    __builtin_amdgcn_sched_barrier(0);
    __builtin_amdgcn_s_setprio(1);
#pragma unroll
    for (int i = 0; i < 4; ++i)
#pragma unroll
      for (int j = 0; j < 2; ++j) {
        acc[i + 4][j + 2] = __builtin_amdgcn_mfma_f32_16x16x32_f16(afr[i][0], b23[j][0], acc[i + 4][j + 2], 0, 0, 0);
        acc[i + 4][j + 2] = __builtin_amdgcn_mfma_f32_16x16x32_f16(afr[i][1], b23[j][1], acc[i + 4][j + 2], 0, 0, 0);
      }
    __builtin_amdgcn_s_setprio(0);
    __builtin_amdgcn_s_barrier();

    // ---- phase 4: MFMA Q(1,0); tile-boundary wait ----
    __builtin_amdgcn_s_setprio(1);
#pragma unroll
    for (int i = 0; i < 4; ++i)
#pragma unroll
      for (int j = 0; j < 2; ++j) {
        acc[i + 4][j] = __builtin_amdgcn_mfma_f32_16x16x32_f16(afr[i][0], b01[j][0], acc[i + 4][j], 0, 0, 0);
        acc[i + 4][j] = __builtin_amdgcn_mfma_f32_16x16x32_f16(afr[i][1], b01[j][1], acc[i + 4][j], 0, 0, 0);
      }
    __builtin_amdgcn_s_setprio(0);
    WAIT_VMCNT0();                  // next tile fully staged (issued by ph2)
    __builtin_amdgcn_s_barrier();
  }

  // epilogue: C/D layout col=lane&15, row=(lane>>4)*4+reg
#pragma unroll
  for (int j = 0; j < 4; ++j) {
    const int col = nb + wn * 64 + j * 16 + l15;
    const float bias = eb[e * HD + col];
#pragma unroll
    for (int i = 0; i < 8; ++i) {
      const int rbase = wm * 128 + i * 16 + (q4 << 2);
#pragma unroll
      for (int r = 0; r < 4; ++r) {
        const int row = rbase + r;
        const float v = w_s[row] * (acc[i][j][r] + bias);
        if (EPI == 1) {
          scratch[(size_t)(sbase + m0 + row) * HD + col] = (_Float16)v;
        } else {
          if (m0 + row < ce)
            atomicAdd(&out[(size_t)tok_s[row] * HD + col], v);
        }
      }
    }
  }
}

// ---- Combine: out[t] = scratch[slot0] + scratch[slot1] ----
__global__ void moe_combine(const _Float16* __restrict__ scratch,
                            const int* __restrict__ slot_of,
                            float* __restrict__ out) {
  const int tid = threadIdx.x;
  const int t = blockIdx.x * 2 + (tid >> 7);
  const int c = (tid & 127) * 8;
  int sa = slot_of[2 * t], sb = slot_of[2 * t + 1];
  half8 a = *(const half8*)&scratch[(size_t)sa * HD + c];
  half8 b = *(const half8*)&scratch[(size_t)sb * HD + c];
  float* o = out + (size_t)t * HD + c;
  float4 o0 = {(float)a[0] + (float)b[0], (float)a[1] + (float)b[1],
               (float)a[2] + (float)b[2], (float)a[3] + (float)b[3]};
  float4 o1 = {(float)a[4] + (float)b[4], (float)a[5] + (float)b[5],
               (float)a[6] + (float)b[6], (float)a[7] + (float)b[7]};
  *(float4*)o = o0;
  *(float4*)(o + 4) = o1;
}

extern "C" void kernel_launch(void* const* d_in, const int* in_sizes, int n_in,
                              void* d_out, int out_size, void* d_ws, size_t ws_size,
                              hipStream_t stream) {
  (void)in_sizes; (void)n_in;
  const float* x  = (const float*)d_in[0];
  const float* rw = (const float*)d_in[1];
  const float* rb = (const float*)d_in[2];
  const float* ew = (const float*)d_in[3];
  const float* eb = (const float*)d_in[4];
  float* out = (float*)d_out;

  // ws layout
  char* w = (char*)d_ws;
  int*   cntp     = (int*)(w + 0);        // NE*64 ints (2 KB)
  int*   basep    = (int*)(w + 2048);     // 8 ints
  int*   hist     = (int*)(w + 2304);     // NE*NGRP ints (16 KB)
  size_t off = 2304 + (size_t)NE * NGRP * 4;
  int*   tok_list = (int*)(w + off);  off += (size_t)SLOTS * 4;
  float* tok_w    = (float*)(w + off); off += (size_t)SLOTS * 4;
  int*   slot_of  = (int*)(w + off);  off += (size_t)TOK * 8;
  int*   epair    = (int*)(w + off);  off += (size_t)TOK * 4;
  float* w1buf    = (float*)(w + off); off += (size_t)TOK * 4;
  off = (off + 255) & ~255ull;
  size_t xh_off = off;
  size_t wh_off = xh_off + (size_t)TOK * HD * 2;
  size_t scr_off = wh_off + (size_t)NE * HD * HD * 2;
  size_t needscr = scr_off + (size_t)SLOTS * HD * 2;
  bool fastscr = ws_size >= needscr;

  if (!fastscr)
    hipMemsetAsync(d_out, 0, (size_t)out_size * sizeof(float), stream);

  _Float16* xh = (_Float16*)(w + xh_off);
  _Float16* wh = (_Float16*)(w + wh_off);
  _Float16* scr = fastscr ? (_Float16*)(w + scr_off) : nullptr;

  score_cvt<<<NGRP + 2048, 256, 0, stream>>>(x, rw, rb, ew, xh, wh,
                                             epair, w1buf, hist);
  moe_scatter<<<NGRP, 256, 0, stream>>>(hist, epair, w1buf, cntp, basep,
                                        tok_list, tok_w, slot_of);

  // grid: x = expert (= XCD id under round-robin dispatch), y = (m,n) tiles;
  // y covers m up to 64 tiles (16384 tokens worst-case), early-out on m0>=ce.
  dim3 grid(NE, 256, 1);
  if (fastscr) {
    moe_gemm<1><<<grid, 512, 0, stream>>>(xh, wh, eb, cntp, basep,
                                          tok_list, tok_w, scr, out);
    moe_combine<<<TOK / 2, 256, 0, stream>>>(scr, slot_of, out);
  } else {
    moe_gemm<0><<<grid, 512, 0, stream>>>(xh, wh, eb, cntp, basep,
                                          tok_list, tok_w, nullptr, out);
  }
}

// Round 4
// 202.222 us; speedup vs baseline: 1.0404x; 1.0404x over previous
//
#include <hip/hip_runtime.h>
#include <hip/hip_bf16.h>
#include <math.h>

// MoE top-2: B=4,S=2048,H=1024,E=8,K=2. fp32 in/out, f16 MFMA compute.
#define TOK 8192
#define HD 1024
#define NE 8
#define SLOTS 18432     // 16384 + per-expert 256-pad (BM=256 tiles)
#define NGRP 512        // 16-token scatter groups
#define GRPSZ 16

typedef _Float16 half8 __attribute__((ext_vector_type(8)));
typedef _Float16 half4v __attribute__((ext_vector_type(4)));
typedef float floatx4 __attribute__((ext_vector_type(4)));

#define WAIT_VMCNT(N) asm volatile("s_waitcnt vmcnt(" #N ")" ::: "memory")
#define WAIT_LGKM0()  asm volatile("s_waitcnt lgkmcnt(0)" ::: "memory")
#define MEMFENCE()    asm volatile("" ::: "memory")

struct CTrue  { static constexpr bool value = true;  };
struct CFalse { static constexpr bool value = false; };

// ---- Fused score + weight-convert (block-role split) ----
__global__ __launch_bounds__(256) void score_cvt(
    const float* __restrict__ x,
    const float* __restrict__ rw,
    const float* __restrict__ rb,
    const float* __restrict__ ew,
    _Float16* __restrict__ xh,
    _Float16* __restrict__ wh,
    int* __restrict__ epair,
    float* __restrict__ w1out,
    int* __restrict__ hist) {          // [NE][NGRP]
  const int tid = threadIdx.x;
  const int blk = blockIdx.x;
  if (blk >= NGRP) {
    const int g = (blk - NGRP) * 256 + tid;
    const float4* src = (const float4*)ew;
    half4v* dst = (half4v*)wh;
#pragma unroll
    for (int j = 0; j < 4; ++j) {
      float4 v = src[g + 524288 * j];
      half4v h = {(_Float16)v.x, (_Float16)v.y, (_Float16)v.z, (_Float16)v.w};
      dst[g + 524288 * j] = h;
    }
    return;
  }
  const int lane = tid & 63;
  const int wid = tid >> 6;
  __shared__ int hcnt[NE];
  if (tid < NE) hcnt[tid] = 0;
  __syncthreads();

#pragma unroll
  for (int i = 0; i < 4; ++i) {
    const int t = blk * GRPSZ + wid * 4 + i;
    const float4* xp = (const float4*)(x + (size_t)t * HD);
    float4 xr[4];
#pragma unroll
    for (int k = 0; k < 4; ++k) xr[k] = xp[lane + 64 * k];
    _Float16* xo = xh + (size_t)t * HD;
#pragma unroll
    for (int k = 0; k < 4; ++k) {
      half4v h = {(_Float16)xr[k].x, (_Float16)xr[k].y,
                  (_Float16)xr[k].z, (_Float16)xr[k].w};
      *(half4v*)(xo + (lane + 64 * k) * 4) = h;
    }
    float sc[NE];
#pragma unroll
    for (int e = 0; e < NE; ++e) {
      const float4* wp = (const float4*)(rw + e * HD);
      float a = 0.f;
#pragma unroll
      for (int k = 0; k < 4; ++k) {
        float4 w = wp[lane + 64 * k];
        a += xr[k].x * w.x + xr[k].y * w.y + xr[k].z * w.z + xr[k].w * w.w;
      }
#pragma unroll
      for (int off = 32; off > 0; off >>= 1) a += __shfl_xor(a, off);
      sc[e] = a + rb[e];
    }
    // top-2, strict > (ties -> lowest index, matches jax.lax.top_k)
    float b1 = sc[0]; int e1 = 0;
#pragma unroll
    for (int e = 1; e < NE; ++e) if (sc[e] > b1) { b1 = sc[e]; e1 = e; }
    float b2 = -1e30f; int e2 = 0;
#pragma unroll
    for (int e = 0; e < NE; ++e) { if (e != e1 && sc[e] > b2) { b2 = sc[e]; e2 = e; } }
    if (lane == 0) {
      epair[t] = e1 | (e2 << 8);
      w1out[t] = 1.f / (1.f + expf(b2 - b1));  // renormalized top-2 softmax
      atomicAdd(&hcnt[e1], 1);
      atomicAdd(&hcnt[e2], 1);
    }
  }
  __syncthreads();
  if (tid < NE) hist[tid * NGRP + blk] = hcnt[tid];
}

// ---- Scatter: each block recomputes its prefix from hist (no global sync) --
__global__ __launch_bounds__(256) void moe_scatter(
    const int* __restrict__ hist,
    const int* __restrict__ epair,
    const float* __restrict__ w1in,
    int* __restrict__ cntp,
    int* __restrict__ basep,
    int* __restrict__ tok_list,
    float* __restrict__ tok_w,
    int* __restrict__ slot_of) {
  const int tid = threadIdx.x;
  const int blk = blockIdx.x;
  __shared__ int pre_s[NE], tot_s[NE], alloc_s[NE];
  {
    const int e = tid >> 5;
    const int sl = tid & 31;
    int p = 0, tt = 0;
#pragma unroll
    for (int j = 0; j < 16; ++j) {
      int g = sl + 32 * j;
      int h = hist[e * NGRP + g];
      tt += h;
      p += (g < blk) ? h : 0;
    }
#pragma unroll
    for (int off = 16; off > 0; off >>= 1) {
      p += __shfl_xor(p, off);
      tt += __shfl_xor(tt, off);
    }
    if (sl == 0) { pre_s[e] = p; tot_s[e] = tt; }
  }
  __syncthreads();
  if (tid == 0) {
    int b = 0;
    for (int e = 0; e < NE; ++e) {
      alloc_s[e] = b + pre_s[e];
      if (blk == 0) { cntp[e * 64] = tot_s[e]; basep[e] = b; }
      b += (tot_s[e] + 255) & ~255;   // 256-pad: BM=256 tiles never straddle
    }
  }
  __syncthreads();
  if (tid < GRPSZ) {
    const int t = blk * GRPSZ + tid;
    int ep = epair[t];
    int e1 = ep & 0xff, e2 = ep >> 8;
    float w1 = w1in[t];
    int s1 = atomicAdd(&alloc_s[e1], 1);
    tok_list[s1] = t; tok_w[s1] = w1; slot_of[2 * t] = s1;
    int s2 = atomicAdd(&alloc_s[e2], 1);
    tok_list[s2] = t; tok_w[s2] = 1.f - w1; slot_of[2 * t + 1] = s2;
  }
}

// ---- Grouped expert GEMM: 256x256, BK=64, 8-wave, 4-phase COUNTED pipeline.
// R3 lessons: (a) expert<->XCD pinning halved occupancy via expert imbalance
// -> unpinned grid: x=n-tile, y=e*32+mt; XCD=(x+4y)%8=n+4*(mt&1): balanced,
// and each XCD still sees only one n-panel per expert (8x512KB=4MB L2-fit).
// (b) vmcnt(0) tile-boundary drain violates T4. Fix: wave tile spans BOTH
// halves (rows wm*64 & wm*64+128; cols wn*32 & wn*32+128) so quadrant phases
// depend on units in sequence; stage order u0=Ah0,u1=Bh0,u2=Bh1,u3=Ah1
// (one unit/phase, 2 loads/wave) gives steady-state waits of vmcnt(6) --
// every unit has 3 phases (~2000 cyc) in flight before its wait. Unit
// regions are overwritten exactly one tile after last read (barrier-split).
// 3-bit XOR chunk swizzle (verified 0 conflicts): chunk g of row r at LDS
// pos g^(r&7); reads use pos cc^(l15&7).
// EPI=1: f16 store to compacted scratch; EPI=0: fp32 atomicAdd to out.
template <int EPI>
__global__ __launch_bounds__(512, 2) void moe_gemm(
    const _Float16* __restrict__ Ah, const _Float16* __restrict__ Bh,
    const float* __restrict__ eb,
    const int* __restrict__ cntp, const int* __restrict__ base,
    const int* __restrict__ tok_list, const float* __restrict__ tok_w,
    _Float16* __restrict__ scratch, float* __restrict__ out) {
  const int ybl = blockIdx.y;
  const int e = ybl >> 5;                  // expert
  const int mt = ybl & 31;                 // m-tile (worst case 8192/256=32)
  const int ce = cntp[e * 64];
  const int m0 = mt << 8;
  if (m0 >= ce) return;
  const int nb = blockIdx.x << 8;          // n-tile * 256
  const int sbase = base[e];
  const int tid = threadIdx.x;
  const int lane = tid & 63;
  const int wid = tid >> 6;                // 0..7
  const int wm = wid >> 2, wn = wid & 3;   // wave: rows {wm*64,+128}, cols {wn*32,+128}

  __shared__ _Float16 A_s[2][256 * 64];
  __shared__ _Float16 B_s[2][256 * 64];
  __shared__ int tok_s[256];
  __shared__ float w_s[256];

  if (tid < 256) {
    int tk = 0; float w = 0.f;
    if (m0 + tid < ce) { tk = tok_list[sbase + m0 + tid]; w = tok_w[sbase + m0 + tid]; }
    tok_s[tid] = tk; w_s[tid] = w;
  }
  __syncthreads();   // drains vmcnt -> clean counter before pipeline

  floatx4 acc[8][4];
  floatx4 zero = {0.f, 0.f, 0.f, 0.f};
#pragma unroll
  for (int i = 0; i < 8; ++i)
#pragma unroll
    for (int j = 0; j < 4; ++j) acc[i][j] = zero;

  const int wbase = e * HD * HD;           // fits int: <= 7*2^20
  // staging: unit = 128 rows (half-tile), 2 global_load_lds per wave
  // (8 rows x 8 chunks x 16B each). u = uh*2 + c.
  const int rloc = lane >> 3, sub = lane & 7;
  const int g8 = (sub ^ rloc) * 8;
  int agoff[4], bgoff[4];
#pragma unroll
  for (int u = 0; u < 4; ++u) {
    const int row = (u >> 1) * 128 + wid * 16 + (u & 1) * 8 + rloc;
    agoff[u] = tok_s[row] * HD + g8;
    bgoff[u] = wbase + (nb + row) * HD + g8;
  }
  const int l15 = lane & 15, q4 = lane >> 4;
  const int ck0 = (q4 ^ (l15 & 7)) * 8;
  const int ck1 = ((4 + q4) ^ (l15 & 7)) * 8;

  auto gl = [](const _Float16* src, _Float16* dst) {
    __builtin_amdgcn_global_load_lds(
        (const __attribute__((address_space(1))) unsigned int*)src,
        (__attribute__((address_space(3))) unsigned int*)dst, 16, 0, 0);
  };
  auto stageA = [&](int uh, int buf, int k0) {
#pragma unroll
    for (int c = 0; c < 2; ++c) {
      const int r0 = uh * 128 + wid * 16 + c * 8;
      gl(Ah + agoff[uh * 2 + c] + k0, &A_s[buf][r0 * 64]);
    }
  };
  auto stageB = [&](int uh, int buf, int k0) {
#pragma unroll
    for (int c = 0; c < 2; ++c) {
      const int r0 = uh * 128 + wid * 16 + c * 8;
      gl(Bh + bgoff[uh * 2 + c] + k0, &B_s[buf][r0 * 64]);
    }
  };
  auto mf = [](half8 a, half8 b, floatx4 c) {
    return __builtin_amdgcn_mfma_f32_16x16x32_f16(a, b, c, 0, 0, 0);
  };

  // prologue: tile 0 units in canonical order u0=Ah0,u1=Bh0,u2=Bh1,u3=Ah1
  stageA(0, 0, 0);
  stageB(0, 0, 0);
  stageB(1, 0, 0);
  stageA(1, 0, 0);

  auto run_tile = [&](int t, auto lastc) {
    constexpr bool LAST = decltype(lastc)::value;
    const int cur = t & 1, nxt = cur ^ 1;
    const int kn = (t + 1) * 64;
    half8 a0[4][2], a1[4][2], b01[2][2], b23[2][2];

    // -- P1: stage Ah0(t+1); wait u0,u1(t); read A0+B0 frags; MFMA Q(0,0) --
    if constexpr (!LAST) { stageA(0, nxt, kn); WAIT_VMCNT(6); }
    else { WAIT_VMCNT(4); }
    __builtin_amdgcn_s_barrier();
    MEMFENCE();
#pragma unroll
    for (int i = 0; i < 4; ++i) {
      const int r = (wm * 64 + i * 16 + l15) * 64;
      a0[i][0] = *(const half8*)&A_s[cur][r + ck0];
      a0[i][1] = *(const half8*)&A_s[cur][r + ck1];
    }
#pragma unroll
    for (int j = 0; j < 2; ++j) {
      const int r = (wn * 32 + j * 16 + l15) * 64;
      b01[j][0] = *(const half8*)&B_s[cur][r + ck0];
      b01[j][1] = *(const half8*)&B_s[cur][r + ck1];
    }
    WAIT_LGKM0();
    __builtin_amdgcn_sched_barrier(0);
    __builtin_amdgcn_s_setprio(1);
#pragma unroll
    for (int i = 0; i < 4; ++i)
#pragma unroll
      for (int j = 0; j < 2; ++j) {
        acc[i][j] = mf(a0[i][0], b01[j][0], acc[i][j]);
        acc[i][j] = mf(a0[i][1], b01[j][1], acc[i][j]);
      }
    __builtin_amdgcn_s_setprio(0);

    // -- P2: stage Bh0(t+1); wait u2(t); read B1 frags; MFMA Q(0,1) --
    if constexpr (!LAST) { stageB(0, nxt, kn); WAIT_VMCNT(6); }
    else { WAIT_VMCNT(2); }
    __builtin_amdgcn_s_barrier();
    MEMFENCE();
#pragma unroll
    for (int j = 0; j < 2; ++j) {
      const int r = (128 + wn * 32 + j * 16 + l15) * 64;
      b23[j][0] = *(const half8*)&B_s[cur][r + ck0];
      b23[j][1] = *(const half8*)&B_s[cur][r + ck1];
    }
    WAIT_LGKM0();
    __builtin_amdgcn_sched_barrier(0);
    __builtin_amdgcn_s_setprio(1);
#pragma unroll
    for (int i = 0; i < 4; ++i)
#pragma unroll
      for (int j = 0; j < 2; ++j) {
        acc[i][j + 2] = mf(a0[i][0], b23[j][0], acc[i][j + 2]);
        acc[i][j + 2] = mf(a0[i][1], b23[j][1], acc[i][j + 2]);
      }
    __builtin_amdgcn_s_setprio(0);

    // -- P3: stage Bh1(t+1); wait u3(t); read A1 frags; MFMA Q(1,1) --
    if constexpr (!LAST) { stageB(1, nxt, kn); WAIT_VMCNT(6); }
    else { WAIT_VMCNT(0); }
    __builtin_amdgcn_s_barrier();
    MEMFENCE();
#pragma unroll
    for (int i = 0; i < 4; ++i) {
      const int r = (128 + wm * 64 + i * 16 + l15) * 64;
      a1[i][0] = *(const half8*)&A_s[cur][r + ck0];
      a1[i][1] = *(const half8*)&A_s[cur][r + ck1];
    }
    WAIT_LGKM0();
    __builtin_amdgcn_sched_barrier(0);
    __builtin_amdgcn_s_setprio(1);
#pragma unroll
    for (int i = 0; i < 4; ++i)
#pragma unroll
      for (int j = 0; j < 2; ++j) {
        acc[i + 4][j + 2] = mf(a1[i][0], b23[j][0], acc[i + 4][j + 2]);
        acc[i + 4][j + 2] = mf(a1[i][1], b23[j][1], acc[i + 4][j + 2]);
      }
    __builtin_amdgcn_s_setprio(0);

    // -- P4: stage Ah1(t+1); MFMA Q(1,0) (register-only) --
    if constexpr (!LAST) stageA(1, nxt, kn);
    __builtin_amdgcn_s_setprio(1);
#pragma unroll
    for (int i = 0; i < 4; ++i)
#pragma unroll
      for (int j = 0; j < 2; ++j) {
        acc[i + 4][j] = mf(a1[i][0], b01[j][0], acc[i + 4][j]);
        acc[i + 4][j] = mf(a1[i][1], b01[j][1], acc[i + 4][j]);
      }
    __builtin_amdgcn_s_setprio(0);
  };

  for (int t = 0; t < 15; ++t) run_tile(t, CFalse{});
  run_tile(15, CTrue{});

  // epilogue: C/D layout col=lane&15, row=(lane>>4)*4+reg; wave tile is
  // split: row half from i>>2 (+128), col half from j>>1 (+128).
#pragma unroll
  for (int j = 0; j < 4; ++j) {
    const int col = nb + wn * 32 + (j & 1) * 16 + (j >> 1) * 128 + l15;
    const float bias = eb[e * HD + col];
#pragma unroll
    for (int i = 0; i < 8; ++i) {
      const int rbase = wm * 64 + (i & 3) * 16 + (i >> 2) * 128 + (q4 << 2);
#pragma unroll
      for (int r = 0; r < 4; ++r) {
        const int row = rbase + r;
        const float v = w_s[row] * (acc[i][j][r] + bias);
        if (EPI == 1) {
          scratch[(size_t)(sbase + m0 + row) * HD + col] = (_Float16)v;
        } else {
          if (m0 + row < ce)
            atomicAdd(&out[(size_t)tok_s[row] * HD + col], v);
        }
      }
    }
  }
}

// ---- Combine: out[t] = scratch[slot0] + scratch[slot1] ----
__global__ void moe_combine(const _Float16* __restrict__ scratch,
                            const int* __restrict__ slot_of,
                            float* __restrict__ out) {
  const int tid = threadIdx.x;
  const int t = blockIdx.x * 2 + (tid >> 7);
  const int c = (tid & 127) * 8;
  int sa = slot_of[2 * t], sb = slot_of[2 * t + 1];
  half8 a = *(const half8*)&scratch[(size_t)sa * HD + c];
  half8 b = *(const half8*)&scratch[(size_t)sb * HD + c];
  float* o = out + (size_t)t * HD + c;
  float4 o0 = {(float)a[0] + (float)b[0], (float)a[1] + (float)b[1],
               (float)a[2] + (float)b[2], (float)a[3] + (float)b[3]};
  float4 o1 = {(float)a[4] + (float)b[4], (float)a[5] + (float)b[5],
               (float)a[6] + (float)b[6], (float)a[7] + (float)b[7]};
  *(float4*)o = o0;
  *(float4*)(o + 4) = o1;
}

extern "C" void kernel_launch(void* const* d_in, const int* in_sizes, int n_in,
                              void* d_out, int out_size, void* d_ws, size_t ws_size,
                              hipStream_t stream) {
  (void)in_sizes; (void)n_in;
  const float* x  = (const float*)d_in[0];
  const float* rw = (const float*)d_in[1];
  const float* rb = (const float*)d_in[2];
  const float* ew = (const float*)d_in[3];
  const float* eb = (const float*)d_in[4];
  float* out = (float*)d_out;

  // ws layout
  char* w = (char*)d_ws;
  int*   cntp     = (int*)(w + 0);        // NE*64 ints (2 KB)
  int*   basep    = (int*)(w + 2048);     // 8 ints
  int*   hist     = (int*)(w + 2304);     // NE*NGRP ints (16 KB)
  size_t off = 2304 + (size_t)NE * NGRP * 4;
  int*   tok_list = (int*)(w + off);  off += (size_t)SLOTS * 4;
  float* tok_w    = (float*)(w + off); off += (size_t)SLOTS * 4;
  int*   slot_of  = (int*)(w + off);  off += (size_t)TOK * 8;
  int*   epair    = (int*)(w + off);  off += (size_t)TOK * 4;
  float* w1buf    = (float*)(w + off); off += (size_t)TOK * 4;
  off = (off + 255) & ~255ull;
  size_t xh_off = off;
  size_t wh_off = xh_off + (size_t)TOK * HD * 2;
  size_t scr_off = wh_off + (size_t)NE * HD * HD * 2;
  size_t needscr = scr_off + (size_t)SLOTS * HD * 2;
  bool fastscr = ws_size >= needscr;

  if (!fastscr)
    hipMemsetAsync(d_out, 0, (size_t)out_size * sizeof(float), stream);

  _Float16* xh = (_Float16*)(w + xh_off);
  _Float16* wh = (_Float16*)(w + wh_off);
  _Float16* scr = fastscr ? (_Float16*)(w + scr_off) : nullptr;

  score_cvt<<<NGRP + 2048, 256, 0, stream>>>(x, rw, rb, ew, xh, wh,
                                             epair, w1buf, hist);
  moe_scatter<<<NGRP, 256, 0, stream>>>(hist, epair, w1buf, cntp, basep,
                                        tok_list, tok_w, slot_of);

  // grid: x = n-tile (4), y = e*32 + mt (worst-case 32 m-tiles/expert).
  // XCD = (x+4y)%8 = n + 4*(mt&1): balanced across experts, one n-panel
  // per expert per XCD (4 MB, L2-fit). Early-out on m0 >= ce.
  dim3 grid(HD / 256, NE * 32, 1);
  if (fastscr) {
    moe_gemm<1><<<grid, 512, 0, stream>>>(xh, wh, eb, cntp, basep,
                                          tok_list, tok_w, scr, out);
    moe_combine<<<TOK / 2, 256, 0, stream>>>(scr, slot_of, out);
  } else {
    moe_gemm<0><<<grid, 512, 0, stream>>>(xh, wh, eb, cntp, basep,
                                          tok_list, tok_w, nullptr, out);
  }
}

// Round 5
// 193.365 us; speedup vs baseline: 1.0880x; 1.0458x over previous
//
#include <hip/hip_runtime.h>
#include <hip/hip_bf16.h>
#include <math.h>

// MoE top-2: B=4,S=2048,H=1024,E=8,K=2. fp32 in/out, f16 MFMA compute.
#define TOK 8192
#define HD 1024
#define NE 8
#define SLOTS 17408     // 16384 + per-expert 128-pad
#define NGRP 512        // 16-token scatter groups
#define GRPSZ 16

typedef _Float16 half8 __attribute__((ext_vector_type(8)));
typedef _Float16 half4v __attribute__((ext_vector_type(4)));
typedef float floatx4 __attribute__((ext_vector_type(4)));

// counted-vmcnt wait: leaves N newest vmem ops in flight (T4)
#define WAIT_VMCNT(N) asm volatile("s_waitcnt vmcnt(" #N ")" ::: "memory")
#define MEMFENCE() asm volatile("" ::: "memory")

// ---- Fused score + weight-convert (block-role split) ----
__global__ __launch_bounds__(256) void score_cvt(
    const float* __restrict__ x,
    const float* __restrict__ rw,
    const float* __restrict__ rb,
    const float* __restrict__ ew,
    _Float16* __restrict__ xh,
    _Float16* __restrict__ wh,
    int* __restrict__ epair,
    float* __restrict__ w1out,
    int* __restrict__ hist) {          // [NE][NGRP]
  const int tid = threadIdx.x;
  const int blk = blockIdx.x;
  if (blk >= NGRP) {
    const int g = (blk - NGRP) * 256 + tid;
    const float4* src = (const float4*)ew;
    half4v* dst = (half4v*)wh;
#pragma unroll
    for (int j = 0; j < 4; ++j) {
      float4 v = src[g + 524288 * j];
      half4v h = {(_Float16)v.x, (_Float16)v.y, (_Float16)v.z, (_Float16)v.w};
      dst[g + 524288 * j] = h;
    }
    return;
  }
  const int lane = tid & 63;
  const int wid = tid >> 6;
  __shared__ int hcnt[NE];
  if (tid < NE) hcnt[tid] = 0;
  __syncthreads();

#pragma unroll
  for (int i = 0; i < 4; ++i) {
    const int t = blk * GRPSZ + wid * 4 + i;
    const float4* xp = (const float4*)(x + (size_t)t * HD);
    float4 xr[4];
#pragma unroll
    for (int k = 0; k < 4; ++k) xr[k] = xp[lane + 64 * k];
    _Float16* xo = xh + (size_t)t * HD;
#pragma unroll
    for (int k = 0; k < 4; ++k) {
      half4v h = {(_Float16)xr[k].x, (_Float16)xr[k].y,
                  (_Float16)xr[k].z, (_Float16)xr[k].w};
      *(half4v*)(xo + (lane + 64 * k) * 4) = h;
    }
    float sc[NE];
#pragma unroll
    for (int e = 0; e < NE; ++e) {
      const float4* wp = (const float4*)(rw + e * HD);
      float a = 0.f;
#pragma unroll
      for (int k = 0; k < 4; ++k) {
        float4 w = wp[lane + 64 * k];
        a += xr[k].x * w.x + xr[k].y * w.y + xr[k].z * w.z + xr[k].w * w.w;
      }
#pragma unroll
      for (int off = 32; off > 0; off >>= 1) a += __shfl_xor(a, off);
      sc[e] = a + rb[e];
    }
    // top-2, strict > (ties -> lowest index, matches jax.lax.top_k)
    float b1 = sc[0]; int e1 = 0;
#pragma unroll
    for (int e = 1; e < NE; ++e) if (sc[e] > b1) { b1 = sc[e]; e1 = e; }
    float b2 = -1e30f; int e2 = 0;
#pragma unroll
    for (int e = 0; e < NE; ++e) { if (e != e1 && sc[e] > b2) { b2 = sc[e]; e2 = e; } }
    if (lane == 0) {
      epair[t] = e1 | (e2 << 8);
      w1out[t] = 1.f / (1.f + expf(b2 - b1));  // renormalized top-2 softmax
      atomicAdd(&hcnt[e1], 1);
      atomicAdd(&hcnt[e2], 1);
    }
  }
  __syncthreads();
  if (tid < NE) hist[tid * NGRP + blk] = hcnt[tid];
}

// ---- Scatter: each block recomputes its prefix from hist (no global sync) --
__global__ __launch_bounds__(256) void moe_scatter(
    const int* __restrict__ hist,
    const int* __restrict__ epair,
    const float* __restrict__ w1in,
    int* __restrict__ cntp,
    int* __restrict__ basep,
    int* __restrict__ tok_list,
    float* __restrict__ tok_w,
    int* __restrict__ slot_of) {
  const int tid = threadIdx.x;
  const int blk = blockIdx.x;
  __shared__ int pre_s[NE], tot_s[NE], alloc_s[NE];
  {
    const int e = tid >> 5;
    const int sl = tid & 31;
    int p = 0, tt = 0;
#pragma unroll
    for (int j = 0; j < 16; ++j) {
      int g = sl + 32 * j;
      int h = hist[e * NGRP + g];
      tt += h;
      p += (g < blk) ? h : 0;
    }
#pragma unroll
    for (int off = 16; off > 0; off >>= 1) {
      p += __shfl_xor(p, off);
      tt += __shfl_xor(tt, off);
    }
    if (sl == 0) { pre_s[e] = p; tot_s[e] = tt; }
  }
  __syncthreads();
  if (tid == 0) {
    int b = 0;
    for (int e = 0; e < NE; ++e) {
      alloc_s[e] = b + pre_s[e];
      if (blk == 0) { cntp[e * 64] = tot_s[e]; basep[e] = b; }
      b += (tot_s[e] + 127) & ~127;
    }
  }
  __syncthreads();
  if (tid < GRPSZ) {
    const int t = blk * GRPSZ + tid;
    int ep = epair[t];
    int e1 = ep & 0xff, e2 = ep >> 8;
    float w1 = w1in[t];
    int s1 = atomicAdd(&alloc_s[e1], 1);
    tok_list[s1] = t; tok_w[s1] = w1; slot_of[2 * t] = s1;
    int s2 = atomicAdd(&alloc_s[e2], 1);
    tok_list[s2] = t; tok_w[s2] = 1.f - w1; slot_of[2 * t + 1] = s2;
  }
}

// ---- Grouped expert GEMM: 128x128 tile, BK=64, 2-buffer + COUNTED vmcnt.
// Inner loop = R2's proven 63 us structure (counted vmcnt(8), raw barriers).
// R4 change: EXPERT<->XCD PINNING (R3 evidence: FETCH 81->28.8 MB) on the
// proven loop. blockIdx.x = expert = XCD id (round-robin dispatch, verified
// R1/R3 via FETCH deltas). blockIdx.y = mt*8+nt: each 64-block concurrency
// window covers 8 m-tiles x all 8 n-tiles -> working set 1 MB A-tiles +
// 2 MB B-panel fits the XCD's 4 MB L2; B fetched ~once per XCD. Expert
// populations are balanced (+-few % on gaussian router) so pinning's
// balance cost is <= 1 generation.
// 3-bit XOR chunk swizzle: global chunk g of row r stored at pos g^(r&7);
// fragment reads pos cc^(l15&7) -> <=2-way bank aliasing (free, 0 measured).
// EPI=1: f16 store to compacted scratch; EPI=0: fp32 atomicAdd to out.
template <int EPI>
__global__ __launch_bounds__(256, 2) void moe_gemm(
    const _Float16* __restrict__ Ah, const _Float16* __restrict__ Bh,
    const float* __restrict__ eb,
    const int* __restrict__ cntp, const int* __restrict__ base,
    const int* __restrict__ tok_list, const float* __restrict__ tok_w,
    _Float16* __restrict__ scratch, float* __restrict__ out) {
  const int e = blockIdx.x;                 // expert == XCD id
  const int ce = cntp[e * 64];
  const int mt = blockIdx.y >> 3;           // m-tile (0..63)
  const int m0 = mt << 7;
  if (m0 >= ce) return;
  const int n0 = (blockIdx.y & 7) << 7;     // n-tile
  const int sbase = base[e];
  const int tid = threadIdx.x;
  const int lane = tid & 63;
  const int wid = tid >> 6;
  const int wm = wid & 1, wn = wid >> 1;

  __shared__ _Float16 A_s[2][128 * 64];
  __shared__ _Float16 B_s[2][128 * 64];
  __shared__ int tok_s[128];
  __shared__ float w_s[128];

  if (tid < 128) {
    int tk = 0; float w = 0.f;
    if (m0 + tid < ce) { tk = tok_list[sbase + m0 + tid]; w = tok_w[sbase + m0 + tid]; }
    tok_s[tid] = tk; w_s[tid] = w;
  }
  __syncthreads();   // also drains vmcnt to 0 -> clean count entering K-loop

  floatx4 acc[4][4];
  floatx4 zero = {0.f, 0.f, 0.f, 0.f};
#pragma unroll
  for (int i = 0; i < 4; ++i)
#pragma unroll
    for (int j = 0; j < 4; ++j) acc[i][j] = zero;

  const int wbase = e * HD * HD;   // fits int: <= 7*2^20
  // staging: 4 instrs/wave for A (+4 for B); each instr = 8 rows x 8 chunks.
  const int rloc = lane >> 3, sub = lane & 7;
  int agoff[4], bgoff[4];
#pragma unroll
  for (int q = 0; q < 4; ++q) {
    int row = wid * 32 + q * 8 + rloc;
    int g = sub ^ (row & 7);
    agoff[q] = tok_s[row] * HD + g * 8;
    bgoff[q] = wbase + (n0 + row) * HD + g * 8;
  }
  const int l15 = lane & 15, q4 = lane >> 4;

  auto stage = [&](int buf, int k0) {
#pragma unroll
    for (int q = 0; q < 4; ++q) {
      const int r0 = wid * 32 + q * 8;
      __builtin_amdgcn_global_load_lds(
          (const __attribute__((address_space(1))) unsigned int*)(Ah + agoff[q] + k0),
          (__attribute__((address_space(3))) unsigned int*)&A_s[buf][r0 * 64], 16, 0, 0);
      __builtin_amdgcn_global_load_lds(
          (const __attribute__((address_space(1))) unsigned int*)(Bh + bgoff[q] + k0),
          (__attribute__((address_space(3))) unsigned int*)&B_s[buf][r0 * 64], 16, 0, 0);
    }
  };

  auto compute = [&](int buf) {
#pragma unroll
    for (int kf = 0; kf < 2; ++kf) {
      half8 afr[4], bfr[4];
      const int cc = kf * 4 + q4;
#pragma unroll
      for (int i = 0; i < 4; ++i)
        afr[i] = *(const half8*)&A_s[buf][(wm * 64 + i * 16 + l15) * 64 + ((cc ^ (l15 & 7)) * 8)];
#pragma unroll
      for (int j = 0; j < 4; ++j)
        bfr[j] = *(const half8*)&B_s[buf][(wn * 64 + j * 16 + l15) * 64 + ((cc ^ (l15 & 7)) * 8)];
#pragma unroll
      for (int i = 0; i < 4; ++i)
#pragma unroll
        for (int j = 0; j < 4; ++j)
          acc[i][j] = __builtin_amdgcn_mfma_f32_16x16x32_f16(afr[i], bfr[j], acc[i][j], 0, 0, 0);
    }
  };

  // K-loop: 16 steps of BK=64, 2-deep pipeline, loads in flight across
  // barriers (counted vmcnt, never drained to 0 in steady state).
  stage(0, 0);                         // vm: 8 (buf0)
  for (int t = 0; t < 15; ++t) {
    stage((t + 1) & 1, (t + 1) * 64);  // vm: 8 cur + 8 next
    WAIT_VMCNT(8);                     // own cur-buf loads retired
    __builtin_amdgcn_s_barrier();      // all waves' cur-buf staged
    MEMFENCE();                        // pin ds_reads below barrier
    compute(t & 1);
    MEMFENCE();                        // pin ds_reads above barrier
    __builtin_amdgcn_s_barrier();      // cur-buf free for overwrite next iter
  }
  WAIT_VMCNT(0);                       // last buf (buf1) staged
  __builtin_amdgcn_s_barrier();
  MEMFENCE();
  compute(1);

  // epilogue: C/D layout col=lane&15, row=(lane>>4)*4+reg
#pragma unroll
  for (int j = 0; j < 4; ++j) {
    int col = n0 + wn * 64 + j * 16 + l15;
    float bias = eb[e * HD + col];
#pragma unroll
    for (int i = 0; i < 4; ++i) {
      int rbase = wm * 64 + i * 16 + (q4 << 2);
#pragma unroll
      for (int r = 0; r < 4; ++r) {
        int row = rbase + r;
        float v = w_s[row] * (acc[i][j][r] + bias);
        if (EPI == 1) {
          scratch[(size_t)(sbase + m0 + row) * HD + col] = (_Float16)v;
        } else {
          if (m0 + row < ce)
            atomicAdd(&out[(size_t)tok_s[row] * HD + col], v);
        }
      }
    }
  }
}

// ---- Combine: out[t] = scratch[slot0] + scratch[slot1] ----
__global__ void moe_combine(const _Float16* __restrict__ scratch,
                            const int* __restrict__ slot_of,
                            float* __restrict__ out) {
  const int tid = threadIdx.x;
  const int t = blockIdx.x * 2 + (tid >> 7);
  const int c = (tid & 127) * 8;
  int sa = slot_of[2 * t], sb = slot_of[2 * t + 1];
  half8 a = *(const half8*)&scratch[(size_t)sa * HD + c];
  half8 b = *(const half8*)&scratch[(size_t)sb * HD + c];
  float* o = out + (size_t)t * HD + c;
  float4 o0 = {(float)a[0] + (float)b[0], (float)a[1] + (float)b[1],
               (float)a[2] + (float)b[2], (float)a[3] + (float)b[3]};
  float4 o1 = {(float)a[4] + (float)b[4], (float)a[5] + (float)b[5],
               (float)a[6] + (float)b[6], (float)a[7] + (float)b[7]};
  *(float4*)o = o0;
  *(float4*)(o + 4) = o1;
}

extern "C" void kernel_launch(void* const* d_in, const int* in_sizes, int n_in,
                              void* d_out, int out_size, void* d_ws, size_t ws_size,
                              hipStream_t stream) {
  (void)in_sizes; (void)n_in;
  const float* x  = (const float*)d_in[0];
  const float* rw = (const float*)d_in[1];
  const float* rb = (const float*)d_in[2];
  const float* ew = (const float*)d_in[3];
  const float* eb = (const float*)d_in[4];
  float* out = (float*)d_out;

  // ws layout
  char* w = (char*)d_ws;
  int*   cntp     = (int*)(w + 0);        // NE*64 ints (2 KB)
  int*   basep    = (int*)(w + 2048);     // 8 ints
  int*   hist     = (int*)(w + 2304);     // NE*NGRP ints (16 KB)
  size_t off = 2304 + (size_t)NE * NGRP * 4;
  int*   tok_list = (int*)(w + off);  off += (size_t)SLOTS * 4;
  float* tok_w    = (float*)(w + off); off += (size_t)SLOTS * 4;
  int*   slot_of  = (int*)(w + off);  off += (size_t)TOK * 8;
  int*   epair    = (int*)(w + off);  off += (size_t)TOK * 4;
  float* w1buf    = (float*)(w + off); off += (size_t)TOK * 4;
  off = (off + 255) & ~255ull;
  size_t xh_off = off;
  size_t wh_off = xh_off + (size_t)TOK * HD * 2;
  size_t scr_off = wh_off + (size_t)NE * HD * HD * 2;
  size_t needscr = scr_off + (size_t)SLOTS * HD * 2;
  bool fastscr = ws_size >= needscr;

  if (!fastscr)
    hipMemsetAsync(d_out, 0, (size_t)out_size * sizeof(float), stream);

  _Float16* xh = (_Float16*)(w + xh_off);
  _Float16* wh = (_Float16*)(w + wh_off);
  _Float16* scr = fastscr ? (_Float16*)(w + scr_off) : nullptr;

  score_cvt<<<NGRP + 2048, 256, 0, stream>>>(x, rw, rb, ew, xh, wh,
                                             epair, w1buf, hist);
  moe_scatter<<<NGRP, 256, 0, stream>>>(hist, epair, w1buf, cntp, basep,
                                        tok_list, tok_w, slot_of);

  // grid: x = expert (= XCD id), y = mt*8 + nt (64 m-tiles x 8 n-tiles);
  // early-out on m0 >= ce. Concurrency window = 8 mt x 8 nt per XCD.
  dim3 grid(NE, 512, 1);
  if (fastscr) {
    moe_gemm<1><<<grid, 256, 0, stream>>>(xh, wh, eb, cntp, basep,
                                          tok_list, tok_w, scr, out);
    moe_combine<<<TOK / 2, 256, 0, stream>>>(scr, slot_of, out);
  } else {
    moe_gemm<0><<<grid, 256, 0, stream>>>(xh, wh, eb, cntp, basep,
                                          tok_list, tok_w, nullptr, out);
  }
}